// Round 1
// baseline (193.617 us; speedup 1.0000x reference)
//
#include <hip/hip_runtime.h>
#include <stdint.h>

typedef unsigned short u16;
typedef __attribute__((ext_vector_type(8)))  short short8;
typedef __attribute__((ext_vector_type(16))) float f32x16;
typedef __attribute__((ext_vector_type(4)))  float f32x4;

#define SAMP 51216        // LDS bytes per sample region (100*512 + 16 pad)
#define LDSB (2*SAMP)     // 102432
#define PACK_BYTES (1920ull*1024ull)
#define ZMASK 0x07AB01AA80EAE0FAull

// boundary sps that stay zero (24), per padded 10x10 grid
__device__ const uint8_t ZSP[24] = {4,5,6,7,8,9,10,19,29,30,39,49,50,59,60,70,80,90,91,92,93,94,96,98};

// per-pixel (0..63) LDS write targets (sp indices), 255 = none
__device__ const uint8_t WSP[64][3] = {
  {11,95,255},{12,255,255},{13,97,255},{14,255,255},{255,255,255},{16,255,255},{17,255,255},{18,255,255},
  {21,69,255},{22,255,255},{23,255,255},{24,255,255},{25,61,255},{255,255,255},{27,255,255},{28,255,255},
  {31,79,255},{32,255,255},{33,255,255},{34,255,255},{35,255,255},{36,255,255},{255,255,255},{38,255,255},
  {41,89,255},{42,255,255},{43,255,255},{44,255,255},{45,255,255},{46,255,255},{47,83,255},{255,255,255},
  {51,15,99},{52,255,255},{53,255,255},{54,255,255},{55,255,255},{56,255,255},{57,255,255},{58,255,255},
  {255,255,255},{62,26,255},{63,255,255},{64,255,255},{65,255,255},{66,255,255},{67,255,255},{68,20,255},
  {71,255,255},{72,255,255},{73,37,255},{74,255,255},{75,255,255},{76,255,255},{77,255,255},{78,255,255},
  {81,255,255},{82,255,255},{255,255,255},{84,0,48},{85,1,255},{86,2,255},{87,3,255},{88,40,255}
};

// tap offsets per direction: 0=up, 1=left, 2=right
__device__ const int8_t TAPR[3][5] = {{0,0,1,2,2},{1,2,2,2,3},{1,2,2,2,3}};
__device__ const int8_t TAPC[3][5] = {{0,1,1,1,2},{1,0,1,2,1},{1,1,2,3,3}};

// padded sp -> source pixel (0..63) or -1 (zero); includes the 18 fixup copies
__device__ const int8_t MAP100[100] = {
  59,60,61,62,-1,-1,-1,-1,-1,-1,
  -1, 0, 1, 2, 3,32, 5, 6, 7,-1,
  47, 8, 9,10,11,12,41,14,15,-1,
  -1,16,17,18,19,20,21,50,23,-1,
  63,24,25,26,27,28,29,30,59,-1,
  -1,32,33,34,35,36,37,38,39,-1,
  -1,12,41,42,43,44,45,46,47, 8,
  -1,48,49,50,51,52,53,54,55,16,
  -1,56,57,30,59,60,61,62,63,24,
  -1,-1,-1,-1,-1, 0,-1, 2,-1,32
};

__device__ __forceinline__ int hsp(int sp) {
  int r = sp / 10;
  int c = sp - r * 10;
  return ((r >> 1) & 3) | ((c & 2) << 1);   // 3-bit bank-slot hash, distinct across a tap's 16 positions
}

__device__ __forceinline__ u16 f2bf(float f) {
  uint32_t u = __float_as_uint(f);
  return (u16)((u + 0x7FFFu + ((u >> 16) & 1)) >> 16);   // RNE
}

// ---------------- weight pre-pack: exact B-fragment order -------------------
// frag = ((d*5+t)*16+cb)*8+nt ; lane l holds B[k=8*(l>>5)+e][n=l&31]
__global__ __launch_bounds__(256) void kag_prep(const float* __restrict__ wU,
                                                const float* __restrict__ wL,
                                                const float* __restrict__ wR,
                                                u16* __restrict__ pack) {
  int tid  = blockIdx.x * 256 + threadIdx.x;     // 0..122879
  int l    = tid & 63;
  int frag = tid >> 6;                           // 0..1919
  int d    = frag / 640;
  int rem  = frag - d * 640;
  int t    = rem >> 7;
  int rem2 = rem & 127;
  int cb   = rem2 >> 3;
  int nt   = rem2 & 7;
  const float* w = (d == 0) ? wU : ((d == 1) ? wL : wR);
  int tr = TAPR[d][t], tc = TAPC[d][t];
  int o  = nt * 32 + (l & 31);
  int c0 = cb * 16 + ((l >> 5) << 3);
  const float* wp = w + (size_t)o * 4096 + (size_t)c0 * 16 + tr * 4 + tc;
  union { u16 u[8]; short8 v; } cv;
#pragma unroll
  for (int e = 0; e < 8; ++e) cv.u[e] = f2bf(wp[e * 16]);
  *(short8*)(pack + (size_t)frag * 512 + l * 8) = cv.v;
}

// ---------------- main kernel: 2 samples/block, MFMA 32x32x16 ---------------
__global__ __launch_bounds__(768, 3) void kag_main(const float* __restrict__ x,
                                                   const u16* __restrict__ pack,
                                                   const float* __restrict__ bU,
                                                   const float* __restrict__ bL,
                                                   const float* __restrict__ bR,
                                                   float* __restrict__ out) {
  extern __shared__ __align__(16) char lds[];
  const int tid = threadIdx.x;
  const int l   = tid & 63;
  const int w   = tid >> 6;          // 0..11
  const int b0  = blockIdx.x * 2;

  // phase 0: zero the never-written boundary rows (both samples)
  for (int idx = tid; idx < 1536; idx += 768) {
    int c8 = idx & 31;
    int t2 = idx >> 5;               // 0..47
    int s  = (t2 >= 24) ? 1 : 0;
    int zi = t2 - s * 24;
    int sp = ZSP[zi];
    int off = s * SAMP + sp * 512 + ((c8 * 16) ^ (hsp(sp) << 4));
    *(short8*)(lds + off) = (short8)(short)0;
  }

  // per-lane write-target precompute
  int wof[3], whh[3];
#pragma unroll
  for (int k2 = 0; k2 < 3; ++k2) {
    int spv = WSP[l][k2];
    wof[k2] = spv * 512;
    whh[k2] = (spv < 255) ? (hsp(spv) << 4) : -1;
  }

  // phase 1: stage 2 samples; lane = pixel, wave covers 8 channels/job
  for (int job = w; job < 64; job += 12) {
    int s  = job >> 5;
    int c0 = (job & 31) * 8;
    const float* xs = x + (size_t)(b0 + s) * 16384 + (size_t)c0 * 64 + l;
    union { u16 u[8]; short8 v; } cv;
#pragma unroll
    for (int e = 0; e < 8; ++e) cv.u[e] = f2bf(xs[e * 64]);
    int c0x = c0 * 2;
    int sb  = s * SAMP;
#pragma unroll
    for (int k2 = 0; k2 < 3; ++k2) {
      if (whh[k2] >= 0)
        *(short8*)(lds + sb + wof[k2] + (c0x ^ whh[k2])) = cv.v;
    }
  }
  __syncthreads();

  // phase 2: MFMA. wave -> (dir = w>>2, n-tiles nt0 = w&3 and nt0+4)
  const int d   = w >> 2;
  const int nt0 = w & 3;
  const int m   = l & 31;
  const int sA  = m >> 4;
  const int pos = m & 15;
  const int i   = pos >> 2, j = pos & 3;
  const int chb2 = (l >> 5) << 4;

  int baseA[5], hx[5];
#pragma unroll
  for (int t = 0; t < 5; ++t) {
    int tr = TAPR[d][t], tc = TAPC[d][t];
    int sp = (2 * i + tr) * 10 + (2 * j + tc);
    int h  = hsp(sp);
    baseA[t] = sA * SAMP + sp * 512 + (chb2 ^ ((h & 1) << 4));
    hx[t]    = (h >> 1) << 5;
  }

  f32x16 acc0, acc1;
#pragma unroll
  for (int r2 = 0; r2 < 16; ++r2) { acc0[r2] = 0.f; acc1[r2] = 0.f; }

  const short8* pk = (const short8*)pack;
  const int fb = d * 640;
#pragma unroll
  for (int cb = 0; cb < 16; ++cb) {
    short8 a[5];
#pragma unroll
    for (int t = 0; t < 5; ++t)
      a[t] = *(const short8*)(lds + baseA[t] + ((cb * 32) ^ hx[t]));
#pragma unroll
    for (int t = 0; t < 5; ++t) {
      int fi = fb + (t * 16 + cb) * 8 + nt0;
      short8 wb0 = pk[(size_t)fi * 64 + l];
      short8 wb1 = pk[(size_t)(fi + 4) * 64 + l];
      acc0 = __builtin_amdgcn_mfma_f32_32x32x16_bf16(a[t], wb0, acc0, 0, 0, 0);
      acc1 = __builtin_amdgcn_mfma_f32_32x32x16_bf16(a[t], wb1, acc1, 0, 0, 0);
    }
  }
  __syncthreads();

  // phase 3: epilogue via LDS out-tile (swizzled), bias + zero-mask, coalesced dump
  const float* bp = (d == 0) ? bU : ((d == 1) ? bL : bR);
  const int ol = l & 31;
  const int o0 = nt0 * 32 + ol;
  const int o1 = o0 + 128;
  const float bias0 = bp[o0];
  const float bias1 = bp[o1];
  const int lh4 = (l >> 5) * 4;
  float* ldsf = (float*)lds;

  for (int s2 = 0; s2 < 2; ++s2) {
#pragma unroll
    for (int r2 = 0; r2 < 16; ++r2) {
      int row = (r2 & 3) + 8 * (r2 >> 2) + lh4;    // C/D row mapping (verified layout)
      if ((row >> 4) == s2) {
        int p2 = row & 15;
        int i2 = p2 >> 2, j2 = p2 & 3;
        int outp = 16 * i2 + 2 * j2 + ((d > 0) ? 8 : 0) + (d >> 1);
        ldsf[o0 * 64 + (outp ^ ((o0 & 15) << 2))] = acc0[r2] + bias0;
        ldsf[o1 * 64 + (outp ^ ((o1 & 15) << 2))] = acc1[r2] + bias1;
      }
    }
    __syncthreads();
    for (int cc = tid; cc < 4096; cc += 768) {
      int o  = cc >> 4, pb = cc & 15;
      f32x4 v = *(f32x4*)(ldsf + o * 64 + ((pb ^ (o & 15)) << 2));
#pragma unroll
      for (int kk = 0; kk < 4; ++kk)
        if ((ZMASK >> (pb * 4 + kk)) & 1ull) v[kk] = 0.f;
      *(f32x4*)(out + (((size_t)(b0 + s2) * 256 + o) << 6) + pb * 4) = v;
    }
    __syncthreads();
  }
}

// ---------------- slow fp32 fallback (only if ws too small) -----------------
__global__ __launch_bounds__(256) void kag_fallback(const float* __restrict__ x,
    const float* __restrict__ wU, const float* __restrict__ bU,
    const float* __restrict__ wL, const float* __restrict__ bL,
    const float* __restrict__ wR, const float* __restrict__ bR,
    float* __restrict__ out) {
  long long tid = (long long)blockIdx.x * 256 + threadIdx.x;
  if (tid >= (long long)2048 * 256 * 48) return;
  int pd = (int)(tid % 48);
  long long rem = tid / 48;
  int o = (int)(rem % 256);
  int b = (int)(rem / 256);
  int d = pd >> 4, pos = pd & 15;
  int i = pos >> 2, j = pos & 3;
  int outp = 16 * i + 2 * j + ((d > 0) ? 8 : 0) + (d >> 1);
  if ((ZMASK >> outp) & 1ull) return;      // stays zero from memset
  const float* ws = (d == 0) ? wU : ((d == 1) ? wL : wR);
  const float* bs = (d == 0) ? bU : ((d == 1) ? bL : bR);
  float acc = bs[o];
  int spv[5], wofs[5];
#pragma unroll
  for (int t = 0; t < 5; ++t) {
    int tr = TAPR[d][t], tc = TAPC[d][t];
    spv[t]  = (2 * i + tr) * 10 + (2 * j + tc);
    wofs[t] = tr * 4 + tc;
  }
  for (int c = 0; c < 256; ++c) {
    const float* xc = x + ((size_t)b * 256 + c) * 64;
    const float* wc = ws + (size_t)o * 4096 + (size_t)c * 16;
#pragma unroll
    for (int t = 0; t < 5; ++t) {
      int px = MAP100[spv[t]];
      if (px >= 0) acc += xc[px] * wc[wofs[t]];
    }
  }
  out[((size_t)b * 256 + o) * 64 + outp] = acc;
}

extern "C" void kernel_launch(void* const* d_in, const int* in_sizes, int n_in,
                              void* d_out, int out_size, void* d_ws, size_t ws_size,
                              hipStream_t stream) {
  const float* x  = (const float*)d_in[0];
  const float* wU = (const float*)d_in[1];
  const float* bU = (const float*)d_in[2];
  const float* wL = (const float*)d_in[3];
  const float* bL = (const float*)d_in[4];
  const float* wR = (const float*)d_in[5];
  const float* bR = (const float*)d_in[6];
  float* out = (float*)d_out;

  if (ws_size >= PACK_BYTES) {
    u16* pack = (u16*)d_ws;
    kag_prep<<<480, 256, 0, stream>>>(wU, wL, wR, pack);
    hipFuncSetAttribute(reinterpret_cast<const void*>(kag_main),
                        hipFuncAttributeMaxDynamicSharedMemorySize, LDSB);
    kag_main<<<1024, 768, LDSB, stream>>>(x, pack, bU, bL, bR, out);
  } else {
    hipMemsetAsync(d_out, 0, (size_t)out_size * 4, stream);
    kag_fallback<<<98304, 256, 0, stream>>>(x, wU, bU, wL, bL, wR, bR, out);
  }
}

// Round 2
// 107.055 us; speedup vs baseline: 1.8086x; 1.8086x over previous
//
#include <hip/hip_runtime.h>
#include <stdint.h>

typedef unsigned short u16;
typedef __attribute__((ext_vector_type(8)))  short short8;
typedef __attribute__((ext_vector_type(16))) float f32x16;
typedef __attribute__((ext_vector_type(4)))  float f32x4;

#define SROW 39424        // per-sample LDS bytes: 77 rows * 512
#define LDSB (4*SROW)     // 157696
#define PACK_BYTES (1920ull*1024ull)
#define ZMASK 0x07AB01AA80EAE0FAull

// per-pixel (0..63) LDS write targets (padded sp indices), 255 = none
__device__ const uint8_t WSP[64][3] = {
  {11,95,255},{12,255,255},{13,97,255},{14,255,255},{255,255,255},{16,255,255},{17,255,255},{18,255,255},
  {21,69,255},{22,255,255},{23,255,255},{24,255,255},{25,61,255},{255,255,255},{27,255,255},{28,255,255},
  {31,79,255},{32,255,255},{33,255,255},{34,255,255},{35,255,255},{36,255,255},{255,255,255},{38,255,255},
  {41,89,255},{42,255,255},{43,255,255},{44,255,255},{45,255,255},{46,255,255},{47,83,255},{255,255,255},
  {51,15,99},{52,255,255},{53,255,255},{54,255,255},{55,255,255},{56,255,255},{57,255,255},{58,255,255},
  {255,255,255},{62,26,255},{63,255,255},{64,255,255},{65,255,255},{66,255,255},{67,255,255},{68,20,255},
  {71,255,255},{72,255,255},{73,37,255},{74,255,255},{75,255,255},{76,255,255},{77,255,255},{78,255,255},
  {81,255,255},{82,255,255},{255,255,255},{84,0,48},{85,1,255},{86,2,255},{87,3,255},{88,40,255}
};

// padded sp -> compact LDS row slot; 76 = shared zero row
__device__ const uint8_t SLOT100[100] = {
   0, 1, 2, 3,76,76,76,76,76,76,
  76, 4, 5, 6, 7, 8, 9,10,11,76,
  12,13,14,15,16,17,18,19,20,76,
  76,21,22,23,24,25,26,27,28,76,
  29,30,31,32,33,34,35,36,37,76,
  76,38,39,40,41,42,43,44,45,76,
  76,46,47,48,49,50,51,52,53,54,
  76,55,56,57,58,59,60,61,62,63,
  76,64,65,66,67,68,69,70,71,72,
  76,76,76,76,76,73,76,74,76,75
};

// tap offsets per direction: 0=up, 1=left, 2=right
__device__ const int8_t TAPR[3][5] = {{0,0,1,2,2},{1,2,2,2,3},{1,2,2,2,3}};
__device__ const int8_t TAPC[3][5] = {{0,1,1,1,2},{1,0,1,2,1},{1,1,2,3,3}};

// padded sp -> source pixel (0..63) or -1 (zero); includes the 18 fixup copies
__device__ const int8_t MAP100[100] = {
  59,60,61,62,-1,-1,-1,-1,-1,-1,
  -1, 0, 1, 2, 3,32, 5, 6, 7,-1,
  47, 8, 9,10,11,12,41,14,15,-1,
  -1,16,17,18,19,20,21,50,23,-1,
  63,24,25,26,27,28,29,30,59,-1,
  -1,32,33,34,35,36,37,38,39,-1,
  -1,12,41,42,43,44,45,46,47, 8,
  -1,48,49,50,51,52,53,54,55,16,
  -1,56,57,30,59,60,61,62,63,24,
  -1,-1,-1,-1,-1, 0,-1, 2,-1,32
};

// 4-bit granule hash: injective per tap, mod-8 residues covered exactly 2x
__device__ __forceinline__ int hsp4(int sp) {
  int r = sp / 10;
  int c = sp - r * 10;
  return ((r >> 1) + 4 * (c >> 1)) & 15;
}

__device__ __forceinline__ u16 f2bf(float f) {
  uint32_t u = __float_as_uint(f);
  return (u16)((u + 0x7FFFu + ((u >> 16) & 1)) >> 16);   // RNE
}

// ---------------- weight pre-pack: exact B-fragment order -------------------
// frag = ((d*5+t)*16+cb)*8+nt ; lane l holds B[k=8*(l>>5)+e][n=l&31]
__global__ __launch_bounds__(256) void kag_prep(const float* __restrict__ wU,
                                                const float* __restrict__ wL,
                                                const float* __restrict__ wR,
                                                u16* __restrict__ pack) {
  int tid  = blockIdx.x * 256 + threadIdx.x;     // 0..122879
  int l    = tid & 63;
  int frag = tid >> 6;                           // 0..1919
  int d    = frag / 640;
  int rem  = frag - d * 640;
  int t    = rem >> 7;
  int rem2 = rem & 127;
  int cb   = rem2 >> 3;
  int nt   = rem2 & 7;
  const float* w = (d == 0) ? wU : ((d == 1) ? wL : wR);
  int tr = TAPR[d][t], tc = TAPC[d][t];
  int o  = nt * 32 + (l & 31);
  int c0 = cb * 16 + ((l >> 5) << 3);
  const float* wp = w + (size_t)o * 4096 + (size_t)c0 * 16 + tr * 4 + tc;
  union { u16 u[8]; short8 v; } cv;
#pragma unroll
  for (int e = 0; e < 8; ++e) cv.u[e] = f2bf(wp[e * 16]);
  *(short8*)(pack + (size_t)frag * 512 + l * 8) = cv.v;
}

// ---------------- main kernel: 4 samples/block, pipelined MFMA --------------
__global__ __launch_bounds__(768, 3) void kag_main(const float* __restrict__ x,
                                                   const u16* __restrict__ pack,
                                                   const float* __restrict__ bU,
                                                   const float* __restrict__ bL,
                                                   const float* __restrict__ bR,
                                                   float* __restrict__ out) {
  extern __shared__ __align__(16) char lds[];
  const int tid = threadIdx.x;
  const int l   = tid & 63;
  const int w   = tid >> 6;          // 0..11
  const int b0  = blockIdx.x * 4;

  // phase 0: zero the shared zero row of each sample region
  if (tid < 128) {
    int s  = tid >> 5;
    int c8 = tid & 31;
    *(short8*)(lds + s * SROW + 76 * 512 + c8 * 16) = (short8)(short)0;
  }

  // per-lane write-target precompute (slot row + hash)
  int wof[3], whh[3];
#pragma unroll
  for (int k2 = 0; k2 < 3; ++k2) {
    int spv = WSP[l][k2];
    if (spv < 255) {
      wof[k2] = SLOT100[spv] * 512;
      whh[k2] = hsp4(spv);
    } else {
      wof[k2] = 0; whh[k2] = -1;
    }
  }

  // phase 1: stage 4 samples; lane = pixel, wave covers 8 channels/job
  for (int job = w; job < 128; job += 12) {
    int s  = job >> 5;
    int c0 = (job & 31) * 8;
    const float* xs = x + (size_t)(b0 + s) * 16384 + (size_t)c0 * 64 + l;
    union { u16 u[8]; short8 v; } cv;
#pragma unroll
    for (int e = 0; e < 8; ++e) cv.u[e] = f2bf(xs[e * 64]);
    int gw = c0 >> 3;                 // channel granule 0..31
    int sb = s * SROW;
#pragma unroll
    for (int k2 = 0; k2 < 3; ++k2) {
      if (whh[k2] >= 0)
        *(short8*)(lds + sb + wof[k2] + ((gw ^ whh[k2]) << 4)) = cv.v;
    }
  }
  __syncthreads();

  // phase 2: MFMA. wave -> (dir = w>>2, n-tile nt0 = w&3 plus nt0+4)
  const int d   = w >> 2;
  const int nt0 = w & 3;
  const int m   = l & 31;
  const int sA  = m >> 4;            // sample within pair
  const int pos = m & 15;
  const int i   = pos >> 2, j = pos & 3;
  const int lh  = l >> 5;            // k-half

  int baseT[5], hbs[5];
#pragma unroll
  for (int t = 0; t < 5; ++t) {
    int tr = TAPR[d][t], tc = TAPC[d][t];
    int r  = 2 * i + tr, c = 2 * j + tc;
    int sp = r * 10 + c;
    baseT[t] = sA * SROW + SLOT100[sp] * 512;
    hbs[t]   = ((hsp4(sp) ^ lh) << 4);
  }

  f32x16 acc[2][2];
#pragma unroll
  for (int p = 0; p < 2; ++p)
#pragma unroll
    for (int h = 0; h < 2; ++h)
#pragma unroll
      for (int r2 = 0; r2 < 16; ++r2) acc[p][h][r2] = 0.f;

  const char* pkc = (const char*)pack + (size_t)((d * 640 + nt0) * 1024) + l * 16;

  short8 wq[3][2];   // B queue, depth 2 (3 live stages)
  short8 aq[2][2];   // A queue, depth 1, [parity][pair]

  // prologue: B stages 0,1 ; A stage 0   (stage s: cb=s/5, t=s%5)
#pragma unroll
  for (int s = 0; s < 2; ++s) {
    const int cb = s / 5, t = s % 5;
    const size_t bo = (size_t)(t * 16 + cb) * 8192;
    wq[s][0] = *(const short8*)(pkc + bo);
    wq[s][1] = *(const short8*)(pkc + bo + 4096);
  }
  {
    const int off = (0 << 5) ^ hbs[0];
    aq[0][0] = *(const short8*)(lds + baseT[0] + off);
    aq[0][1] = *(const short8*)(lds + baseT[0] + 2 * SROW + off);
  }

#pragma unroll
  for (int s = 0; s < 80; ++s) {
    const int cb = s / 5, t = s - cb * 5;
    if (s + 2 < 80) {                       // prefetch B, depth 2
      const int s2 = s + 2, cb2 = s2 / 5, t2 = s2 - cb2 * 5;
      const size_t bo = (size_t)(t2 * 16 + cb2) * 8192;
      wq[s2 % 3][0] = *(const short8*)(pkc + bo);
      wq[s2 % 3][1] = *(const short8*)(pkc + bo + 4096);
    }
    if (s + 1 < 80) {                       // prefetch A, depth 1
      const int s1 = s + 1, cb1 = s1 / 5, t1 = s1 - cb1 * 5;
      const int off = (cb1 << 5) ^ hbs[t1];
      aq[s1 & 1][0] = *(const short8*)(lds + baseT[t1] + off);
      aq[s1 & 1][1] = *(const short8*)(lds + baseT[t1] + 2 * SROW + off);
    }
    acc[0][0] = __builtin_amdgcn_mfma_f32_32x32x16_bf16(aq[s & 1][0], wq[s % 3][0], acc[0][0], 0, 0, 0);
    acc[0][1] = __builtin_amdgcn_mfma_f32_32x32x16_bf16(aq[s & 1][0], wq[s % 3][1], acc[0][1], 0, 0, 0);
    acc[1][0] = __builtin_amdgcn_mfma_f32_32x32x16_bf16(aq[s & 1][1], wq[s % 3][0], acc[1][0], 0, 0, 0);
    acc[1][1] = __builtin_amdgcn_mfma_f32_32x32x16_bf16(aq[s & 1][1], wq[s % 3][1], acc[1][1], 0, 0, 0);
  }
  __syncthreads();

  // phase 3: epilogue via LDS out-tile (swizzled), bias + zero-mask
  const float* bp = (d == 0) ? bU : ((d == 1) ? bL : bR);
  const int ol = l & 31;
  const int o0 = nt0 * 32 + ol;
  const int o1 = o0 + 128;
  const float bias0 = bp[o0];
  const float bias1 = bp[o1];
  const int lh4 = lh * 4;
  float* ldsf = (float*)lds;

#pragma unroll
  for (int s4 = 0; s4 < 4; ++s4) {
    const int p  = s4 >> 1;
    const int hs = s4 & 1;
#pragma unroll
    for (int r2 = 0; r2 < 16; ++r2) {
      int row = (r2 & 3) + 8 * (r2 >> 2) + lh4;    // C/D row mapping (verified)
      if ((row >> 4) == hs) {
        int p2 = row & 15;
        int i2 = p2 >> 2, j2 = p2 & 3;
        int outp = 16 * i2 + 2 * j2 + ((d > 0) ? 8 : 0) + (d >> 1);
        ldsf[o0 * 64 + (outp ^ ((o0 & 15) << 2))] = acc[p][0][r2] + bias0;
        ldsf[o1 * 64 + (outp ^ ((o1 & 15) << 2))] = acc[p][1][r2] + bias1;
      }
    }
    __syncthreads();
    for (int cc = tid; cc < 4096; cc += 768) {
      int o  = cc >> 4, pb = cc & 15;
      f32x4 v = *(f32x4*)(ldsf + o * 64 + ((pb ^ (o & 15)) << 2));
#pragma unroll
      for (int kk = 0; kk < 4; ++kk)
        if ((ZMASK >> (pb * 4 + kk)) & 1ull) v[kk] = 0.f;
      *(f32x4*)(out + (((size_t)(b0 + s4) * 256 + o) << 6) + pb * 4) = v;
    }
    __syncthreads();
  }
}

// ---------------- slow fp32 fallback (only if ws too small) -----------------
__global__ __launch_bounds__(256) void kag_fallback(const float* __restrict__ x,
    const float* __restrict__ wU, const float* __restrict__ bU,
    const float* __restrict__ wL, const float* __restrict__ bL,
    const float* __restrict__ wR, const float* __restrict__ bR,
    float* __restrict__ out) {
  long long tid = (long long)blockIdx.x * 256 + threadIdx.x;
  if (tid >= (long long)2048 * 256 * 48) return;
  int pd = (int)(tid % 48);
  long long rem = tid / 48;
  int o = (int)(rem % 256);
  int b = (int)(rem / 256);
  int d = pd >> 4, pos = pd & 15;
  int i = pos >> 2, j = pos & 3;
  int outp = 16 * i + 2 * j + ((d > 0) ? 8 : 0) + (d >> 1);
  if ((ZMASK >> outp) & 1ull) return;
  const float* ws = (d == 0) ? wU : ((d == 1) ? wL : wR);
  const float* bs = (d == 0) ? bU : ((d == 1) ? bL : bR);
  float acc = bs[o];
  int spv[5], wofs[5];
#pragma unroll
  for (int t = 0; t < 5; ++t) {
    int tr = TAPR[d][t], tc = TAPC[d][t];
    spv[t]  = (2 * i + tr) * 10 + (2 * j + tc);
    wofs[t] = tr * 4 + tc;
  }
  for (int c = 0; c < 256; ++c) {
    const float* xc = x + ((size_t)b * 256 + c) * 64;
    const float* wc = ws + (size_t)o * 4096 + (size_t)c * 16;
#pragma unroll
    for (int t = 0; t < 5; ++t) {
      int px = MAP100[spv[t]];
      if (px >= 0) acc += xc[px] * wc[wofs[t]];
    }
  }
  out[((size_t)b * 256 + o) * 64 + outp] = acc;
}

extern "C" void kernel_launch(void* const* d_in, const int* in_sizes, int n_in,
                              void* d_out, int out_size, void* d_ws, size_t ws_size,
                              hipStream_t stream) {
  const float* x  = (const float*)d_in[0];
  const float* wU = (const float*)d_in[1];
  const float* bU = (const float*)d_in[2];
  const float* wL = (const float*)d_in[3];
  const float* bL = (const float*)d_in[4];
  const float* wR = (const float*)d_in[5];
  const float* bR = (const float*)d_in[6];
  float* out = (float*)d_out;

  if (ws_size >= PACK_BYTES) {
    u16* pack = (u16*)d_ws;
    kag_prep<<<480, 256, 0, stream>>>(wU, wL, wR, pack);
    hipFuncSetAttribute(reinterpret_cast<const void*>(kag_main),
                        hipFuncAttributeMaxDynamicSharedMemorySize, LDSB);
    kag_main<<<512, 768, LDSB, stream>>>(x, pack, bU, bL, bR, out);
  } else {
    hipMemsetAsync(d_out, 0, (size_t)out_size * 4, stream);
    kag_fallback<<<98304, 256, 0, stream>>>(x, wU, bU, wL, bL, wR, bR, out);
  }
}